// Round 5
// baseline (1413.598 us; speedup 1.0000x reference)
//
#include <hip/hip_runtime.h>

// QuantizedLinear via int8 MFMA, 256x128-tile GEMM, K-slot phases,
// per-slot batched drain. out[M,N] = x[M,K] @ W[N,K]^T + bias.
// W int4 exact in i8, x per-row i8. BK=128 = one scale group; i32 accumulate
// within a K=64 slot (exact), drained to f32 with group scale per slot.
//
// HARD CONSTRAINT (R1/R2/R4 evidence): this toolchain allocates at most
// 128 VGPRs to these 512-thread kernels regardless of launch_bounds /
// waves_per_eu. R4's chained ci[4][4] (64) + accf (64) demanded ~200 ->
// spilled 360 MB/dispatch. This version keeps ci transient per mi-batch:
// peak live ~ accf 64 + bF 16 + aF 8 + ci 16 + sj 8 + addr ~12 <= 128.
// Cost: drain VALU 2x (256 ops/wave/tile ~ 1024 cyc/SIMD) but < MFMA
// (1172 cyc/SIMD/tile) and they co-issue on separate pipes.

typedef int i32x4 __attribute__((ext_vector_type(4)));

#define GAS __attribute__((address_space(1)))
#define LAS __attribute__((address_space(3)))

static constexpr int M_DIM = 8192;
static constexpr int N_DIM = 4096;
static constexpr int K_DIM = 4096;

// ---------------- x fp32 -> i8 per-row (one block per row of 4096) ----------------
__global__ __launch_bounds__(256) void quant_x(const float* __restrict__ x,
                                               signed char* __restrict__ xq,
                                               float* __restrict__ sx) {
    const int row = blockIdx.x;
    const int tid = threadIdx.x;
    const float* xr = x + (size_t)row * K_DIM;
    float4 v[4];
#pragma unroll
    for (int i = 0; i < 4; ++i) v[i] = *(const float4*)(xr + i * 1024 + tid * 4);
    float m = 0.f;
#pragma unroll
    for (int i = 0; i < 4; ++i)
        m = fmaxf(m, fmaxf(fmaxf(fabsf(v[i].x), fabsf(v[i].y)),
                           fmaxf(fabsf(v[i].z), fabsf(v[i].w))));
#pragma unroll
    for (int off = 32; off >= 1; off >>= 1) m = fmaxf(m, __shfl_xor(m, off, 64));
    __shared__ float wm[4];
    if ((tid & 63) == 0) wm[tid >> 6] = m;
    __syncthreads();
    m = fmaxf(fmaxf(wm[0], wm[1]), fmaxf(wm[2], wm[3]));
    const float inv = 127.f / m;
    if (tid == 0) sx[row] = m / 127.f;
#pragma unroll
    for (int i = 0; i < 4; ++i) {
        int b0 = (int)rintf(v[i].x * inv) & 255;
        int b1 = (int)rintf(v[i].y * inv) & 255;
        int b2 = (int)rintf(v[i].z * inv) & 255;
        int b3 = (int)rintf(v[i].w * inv) & 255;
        *(int*)(xq + (size_t)row * K_DIM + i * 1024 + tid * 4) =
            b0 | (b1 << 8) | (b2 << 16) | (b3 << 24);
    }
}

// ---------------- packed int4 -> raw i8 (values q-8 in [-8,7], NO scale) ----------------
__global__ __launch_bounds__(256) void unpack_w(const int* __restrict__ wp,
                                                signed char* __restrict__ wq) {
    const int t = blockIdx.x * 256 + threadIdx.x;   // 4 packed words -> 8 bytes out
    int4 p = *(const int4*)(wp + (size_t)t * 4);
    int pv[4] = {p.x, p.y, p.z, p.w};
    int w01 = (((pv[0] & 15) - 8) & 255) | (((((pv[0] >> 4) & 15) - 8) & 255) << 8) |
              ((((pv[1] & 15) - 8) & 255) << 16) | (((((pv[1] >> 4) & 15) - 8) & 255) << 24);
    int w23 = (((pv[2] & 15) - 8) & 255) | (((((pv[2] >> 4) & 15) - 8) & 255) << 8) |
              ((((pv[3] & 15) - 8) & 255) << 16) | (((((pv[3] >> 4) & 15) - 8) & 255) << 24);
    *(int2*)(wq + (size_t)t * 8) = make_int2(w01, w23);
}

// ---------------- scales [N][32] -> scalesT [32][N] (coalesced gemm reads) ----------------
__global__ __launch_bounds__(256) void transp_scales(const float* __restrict__ s,
                                                     float* __restrict__ st) {
    const int t = blockIdx.x * 256 + threadIdx.x;   // over 4096*32
    st[(size_t)(t & 31) * N_DIM + (t >> 5)] = s[t];
}

// ---------------- i8 GEMM, B^T, 256x128 tile, BK=128, K-slot phases ----------------
// 512 thr = 8 waves (4M x 2N); per-wave output 64x64 = 4x4 frags of 16x16.
// LDS 96 KiB: A [2buf][256 x 128 B] (64 KiB), B [2buf][128 x 128 B] (32 KiB @ +64 KiB).
// Row = 128 B = 8 chunks of 16 B; chunk c stored at slot c ^ (row&7).
// Iteration = 2 K-tiles: t0=2it (buf0: ph1=ks0, ph2=ks1), t1=2it+1 (buf1: ph3, ph4).
// Phase = one K=64 slot over the wave's 64x64 tile: 4 bF reads, then 4 batches
// {1 aF read, 4 MFMA (izero-init), 16-elem drain} -> ci never lives across phases.
//
// Staging: ph1: A(t1)+B(t1)->buf1 [6]; ph2: sjA<-sj(t0+2) [4];
//          ph3: A(t0+2)+B(t0+2)->buf0 [6]; ph4: sjB<-sj(t0+3) [4].
// Ledger (DMA guards only; sj loads are register-tracked by the compiler):
//   end-ph1: ph2 re-reads buf0 (staged 2+ phases ago, already guarded) -> clobber
//   end-ph2: ph3 reads buf1 (ph1's 6): newer = ph2 sj[4]              -> vmcnt(4)
//   end-ph3: ph4 re-reads buf1 (guarded)                              -> clobber
//   end-ph4: ph1' reads buf0 (ph3's 6): newer = ph4 sj[4]             -> vmcnt(4)
// Never vmcnt(0) in loop; max ~10 outstanding; 3-phase prefetch distance.

#define STAGE_A(BUF, TAU) do { \
  _Pragma("unroll") \
  for (int r_ = 0; r_ < 4; ++r_) { \
    const int rbase_ = (r_ * 8 + wv) * 8; \
    const int c_ = (l & 7) ^ (l >> 3); \
    const signed char* sA_ = Aq + (size_t)(m0 + rbase_ + (l >> 3)) * K_DIM \
                                + (size_t)(TAU) * 128 + c_ * 16; \
    __builtin_amdgcn_global_load_lds((const GAS void*)sA_, \
        (LAS void*)(lds + (BUF) * 32768 + rbase_ * 128), 16, 0, 0); \
  } \
} while (0)

#define STAGE_B(BUF, TAU) do { \
  _Pragma("unroll") \
  for (int r_ = 0; r_ < 2; ++r_) { \
    const int rbase_ = (r_ * 8 + wv) * 8; \
    const int c_ = (l & 7) ^ (l >> 3); \
    const signed char* sB_ = Bq + (size_t)(n0 + rbase_ + (l >> 3)) * K_DIM \
                                + (size_t)(TAU) * 128 + c_ * 16; \
    __builtin_amdgcn_global_load_lds((const GAS void*)sB_, \
        (LAS void*)(lds + 65536 + (BUF) * 16384 + rbase_ * 128), 16, 0, 0); \
  } \
} while (0)

#define LOAD_SJ(DST, G) do { \
  _Pragma("unroll") \
  for (int j_ = 0; j_ < 4; ++j_) \
    DST[j_] = scalesT[(size_t)(G) * N_DIM + n0 + wc * 64 + j_ * 16 + lr]; \
} while (0)

// One K=64 slot: 4 bF reads, then 4x { 1 aF read, 4 MFMA, drain 16 into accf }.
#define PHASE(B, KS, SJ) do { \
  i32x4 bF_[4]; \
  _Pragma("unroll") \
  for (int nj = 0; nj < 4; ++nj) { \
    const int rb = wc * 64 + nj * 16 + lr; \
    bF_[nj] = *(const i32x4*)(lds + 65536 + (B) * 16384 + rb * 128 \
                              + ((((KS) * 4 + quad) ^ (rb & 7)) << 4)); \
  } \
  _Pragma("unroll") \
  for (int mi = 0; mi < 4; ++mi) { \
    const int ra = wr * 64 + mi * 16 + lr; \
    const i32x4 aF_ = *(const i32x4*)(lds + (B) * 32768 + ra * 128 \
                                      + ((((KS) * 4 + quad) ^ (ra & 7)) << 4)); \
    __builtin_amdgcn_s_setprio(1); \
    const i32x4 c0_ = __builtin_amdgcn_mfma_i32_16x16x64_i8(aF_, bF_[0], izero, 0, 0, 0); \
    const i32x4 c1_ = __builtin_amdgcn_mfma_i32_16x16x64_i8(aF_, bF_[1], izero, 0, 0, 0); \
    const i32x4 c2_ = __builtin_amdgcn_mfma_i32_16x16x64_i8(aF_, bF_[2], izero, 0, 0, 0); \
    const i32x4 c3_ = __builtin_amdgcn_mfma_i32_16x16x64_i8(aF_, bF_[3], izero, 0, 0, 0); \
    __builtin_amdgcn_s_setprio(0); \
    _Pragma("unroll") \
    for (int r = 0; r < 4; ++r) { \
      accf[mi][0][r] += (SJ)[0] * (float)c0_[r]; \
      accf[mi][1][r] += (SJ)[1] * (float)c1_[r]; \
      accf[mi][2][r] += (SJ)[2] * (float)c2_[r]; \
      accf[mi][3][r] += (SJ)[3] * (float)c3_[r]; \
    } \
  } \
} while (0)

#define VMW(N) asm volatile("s_waitcnt vmcnt(" #N ")" ::: "memory")
#define CLB()  asm volatile("" ::: "memory")
// Barrier + post-clobber so next phase's ds_reads cannot float above s_barrier.
#define BAR()  do { __builtin_amdgcn_s_barrier(); asm volatile("" ::: "memory"); } while (0)

__global__ __launch_bounds__(512)
__attribute__((amdgpu_waves_per_eu(2, 2)))
void gemm_i8(const signed char* __restrict__ Aq,
             const signed char* __restrict__ Bq,
             const float* __restrict__ scalesT,
             const float* __restrict__ sx,
             const float* __restrict__ bias,
             float* __restrict__ C) {
    __shared__ signed char lds[98304];

    const int tid  = threadIdx.x;
    const int l    = tid & 63;
    const int wv   = tid >> 6;      // 0..7
    const int wr   = wv >> 1;       // 0..3  (M quarter of 256)
    const int wc   = wv & 1;        // 0..1  (N half of 128)
    const int lr   = l & 15;
    const int quad = l >> 4;

    // XCD-aware swizzle: 1024 wgs = 8 XCDs x 128; per-XCD 8x16 tile rect (bijective).
    const int bid = blockIdx.x;
    const int xcd = bid & 7, kk = bid >> 3;          // kk in [0,128)
    const int by = (xcd >> 1) * 8 + (kk & 7);        // m-tile 0..31 (256-row tiles)
    const int bx = (xcd & 1) * 16 + (kk >> 3);       // n-tile 0..31 (128-col tiles)
    const int m0 = by * 256, n0 = bx * 128;

    float accf[4][4][4];
#pragma unroll
    for (int i = 0; i < 4; ++i)
#pragma unroll
        for (int j = 0; j < 4; ++j)
#pragma unroll
            for (int r = 0; r < 4; ++r) accf[i][j][r] = 0.f;

    const i32x4 izero = {0, 0, 0, 0};
    float sjA[4], sjB[4];

    // Prologue: stage tile 0 -> buf0 [6], scales for tiles 0 (sjA) and 1 (sjB).
    // vmcnt(8) guards the 6 DMA loads; sj loads are register-tracked.
    STAGE_A(0, 0);
    STAGE_B(0, 0);
    LOAD_SJ(sjA, 0);
    LOAD_SJ(sjB, 1);
    VMW(8);
    BAR();

#pragma unroll 1
    for (int it = 0; it < 16; ++it) {
        const int t1  = it * 2 + 1;
        const int tn0 = (it * 2 + 2) & 31;
        const int tn1 = (it * 2 + 3) & 31;

        // ph1: compute buf0 ks0 (t0); stage A(t1)+B(t1) -> buf1
        STAGE_A(1, t1);
        STAGE_B(1, t1);
        PHASE(0, 0, sjA);
        CLB(); BAR();

        // ph2: compute buf0 ks1 (t0); then reload sjA <- sj(t0+2)
        PHASE(0, 1, sjA);
        LOAD_SJ(sjA, tn0);
        VMW(4); BAR();

        // ph3: compute buf1 ks0 (t1); stage A(t0+2)+B(t0+2) -> buf0
        STAGE_A(0, tn0);
        STAGE_B(0, tn0);
        PHASE(1, 0, sjB);
        CLB(); BAR();

        // ph4: compute buf1 ks1 (t1); then reload sjB <- sj(t0+3)
        PHASE(1, 1, sjB);
        LOAD_SJ(sjB, tn1);
        VMW(4); BAR();
    }

    // Drain leftover wrap-staged DMA before the block exits.
    asm volatile("s_waitcnt vmcnt(0)" ::: "memory");

    // Epilogue: C/D layout col=lane&15, row=quad*4+reg (verified, dtype-independent)
    float sxr[4][4];
#pragma unroll
    for (int i = 0; i < 4; ++i)
#pragma unroll
        for (int r = 0; r < 4; ++r)
            sxr[i][r] = sx[m0 + wr * 64 + i * 16 + quad * 4 + r];
#pragma unroll
    for (int j = 0; j < 4; ++j) {
        const int gn = n0 + wc * 64 + j * 16 + lr;
        const float bv = bias[gn];
#pragma unroll
        for (int i = 0; i < 4; ++i) {
            const size_t gm = (size_t)m0 + wr * 64 + i * 16 + quad * 4;
#pragma unroll
            for (int r = 0; r < 4; ++r)
                C[(gm + r) * N_DIM + gn] = accf[i][j][r] * sxr[i][r] + bv;
        }
    }
}

extern "C" void kernel_launch(void* const* d_in, const int* in_sizes, int n_in,
                              void* d_out, int out_size, void* d_ws, size_t ws_size,
                              hipStream_t stream) {
    const float* x      = (const float*)d_in[0];   // [4,2048,4096] fp32
    const int*   wp     = (const int*)d_in[1];     // [4096,2048] int32 (uint8 semantics)
    const float* scales = (const float*)d_in[2];   // [4096,32]
    const float* bias   = (const float*)d_in[4];   // [4096]
    float* out = (float*)d_out;

    signed char* Xq = (signed char*)d_ws;                                   // 32 MB
    signed char* Wq = (signed char*)d_ws + (size_t)M_DIM * K_DIM;           // +16 MB
    float* sx  = (float*)((char*)d_ws + (size_t)M_DIM * K_DIM + (size_t)N_DIM * K_DIM);          // +32 KB
    float* scT = (float*)((char*)d_ws + (size_t)M_DIM * K_DIM + (size_t)N_DIM * K_DIM + 32768);  // +512 KB

    quant_x<<<M_DIM, 256, 0, stream>>>(x, Xq, sx);
    unpack_w<<<(N_DIM * (K_DIM / 2) / 4) / 256, 256, 0, stream>>>(wp, Wq);
    transp_scales<<<(N_DIM * 32) / 256, 256, 0, stream>>>(scales, scT);
    gemm_i8<<<dim3(1024), 512, 0, stream>>>(Xq, Wq, scT, sx, bias, out);
}

// Round 6
// 429.128 us; speedup vs baseline: 3.2941x; 3.2941x over previous
//
#include <hip/hip_runtime.h>

// QuantizedLinear via int8 MFMA. 256x128-tile GEMM, 1024 threads (16 waves,
// 4/SIMD), triple-buffered LDS, counted vmcnt(3) (never 0 in loop).
// out[M,N] = x[M,K] @ W[N,K]^T + bias; W int4 exact in i8, x per-row i8.
// BK=128 = one scale group; ci chains i32 over the group (exact), one f32
// drain per tile with group scale.
//
// DESIGN RULE (R1-R5 evidence): this toolchain gives these kernels <=128
// arch VGPRs no matter what attributes say; anything bigger spills GBs of
// scratch. At 4 waves/SIMD the HW budget IS 128/wave - design to it:
// accf[4][2][4]=32 + ci[4][2]=32 + aF 16 + bF 8 + sj/addr ~20 ~= 110.
// 16 waves also give real TLP to hide LDS latency (R3's 2/SIMD lockstep
// exposed it: MfmaUtil 26%).

typedef int i32x4 __attribute__((ext_vector_type(4)));

#define GAS __attribute__((address_space(1)))
#define LAS __attribute__((address_space(3)))

static constexpr int M_DIM = 8192;
static constexpr int N_DIM = 4096;
static constexpr int K_DIM = 4096;

// ---------------- x fp32 -> i8 per-row (one block per row of 4096) ----------------
__global__ __launch_bounds__(256) void quant_x(const float* __restrict__ x,
                                               signed char* __restrict__ xq,
                                               float* __restrict__ sx) {
    const int row = blockIdx.x;
    const int tid = threadIdx.x;
    const float* xr = x + (size_t)row * K_DIM;
    float4 v[4];
#pragma unroll
    for (int i = 0; i < 4; ++i) v[i] = *(const float4*)(xr + i * 1024 + tid * 4);
    float m = 0.f;
#pragma unroll
    for (int i = 0; i < 4; ++i)
        m = fmaxf(m, fmaxf(fmaxf(fabsf(v[i].x), fabsf(v[i].y)),
                           fmaxf(fabsf(v[i].z), fabsf(v[i].w))));
#pragma unroll
    for (int off = 32; off >= 1; off >>= 1) m = fmaxf(m, __shfl_xor(m, off, 64));
    __shared__ float wm[4];
    if ((tid & 63) == 0) wm[tid >> 6] = m;
    __syncthreads();
    m = fmaxf(fmaxf(wm[0], wm[1]), fmaxf(wm[2], wm[3]));
    const float inv = 127.f / m;
    if (tid == 0) sx[row] = m / 127.f;
#pragma unroll
    for (int i = 0; i < 4; ++i) {
        int b0 = (int)rintf(v[i].x * inv) & 255;
        int b1 = (int)rintf(v[i].y * inv) & 255;
        int b2 = (int)rintf(v[i].z * inv) & 255;
        int b3 = (int)rintf(v[i].w * inv) & 255;
        *(int*)(xq + (size_t)row * K_DIM + i * 1024 + tid * 4) =
            b0 | (b1 << 8) | (b2 << 16) | (b3 << 24);
    }
}

// ---------------- packed int4 -> raw i8 (values q-8 in [-8,7], NO scale) ----------------
__global__ __launch_bounds__(256) void unpack_w(const int* __restrict__ wp,
                                                signed char* __restrict__ wq) {
    const int t = blockIdx.x * 256 + threadIdx.x;   // 4 packed words -> 8 bytes out
    int4 p = *(const int4*)(wp + (size_t)t * 4);
    int pv[4] = {p.x, p.y, p.z, p.w};
    int w01 = (((pv[0] & 15) - 8) & 255) | (((((pv[0] >> 4) & 15) - 8) & 255) << 8) |
              ((((pv[1] & 15) - 8) & 255) << 16) | (((((pv[1] >> 4) & 15) - 8) & 255) << 24);
    int w23 = (((pv[2] & 15) - 8) & 255) | (((((pv[2] >> 4) & 15) - 8) & 255) << 8) |
              ((((pv[3] & 15) - 8) & 255) << 16) | (((((pv[3] >> 4) & 15) - 8) & 255) << 24);
    *(int2*)(wq + (size_t)t * 8) = make_int2(w01, w23);
}

// ---------------- scales [N][32] -> scalesT [32][N] (coalesced gemm reads) ----------------
__global__ __launch_bounds__(256) void transp_scales(const float* __restrict__ s,
                                                     float* __restrict__ st) {
    const int t = blockIdx.x * 256 + threadIdx.x;   // over 4096*32
    st[(size_t)(t & 31) * N_DIM + (t >> 5)] = s[t];
}

// ---------------- i8 GEMM, B^T, 256x128 tile, BK=128, 3-buffer pipeline ----------------
// 1024 thr = 16 waves (4M x 4N); per-wave output 64x32 = 4x2 frags of 16x16.
// LDS 144 KiB: 3 slots of { A 256x128B (32 KB) | B 128x128B (16 KB) }.
// Row = 128 B = 8 chunks of 16 B; chunk c stored at slot c ^ (row&7) (0-conflict,
// verified lineage). Staging: 3 gload_lds/thread/tile (A 2, B 1), linear dest.
//
// Pipeline (2-tile prefetch distance):
//   prologue: stage t0->s0, t1->s1; vmcnt(3); barrier           [t1 in flight]
//   iter t:   sj loads (2) ; stage t+2 -> (t+2)%3 (3)
//             compute slot t%3: 2 K-slots x {6 ds_read_b128, 8 MFMA},
//             ci chained i32 over BK=128, drain 64 elems w/ sj
//             vmcnt(3) [leaves t+2's 3 in flight]; barrier
// FIFO note: the drain's implicit wait on sj also retires tile t+1's stage
// (older in FIFO) - harmless, t+1 had a full tile of flight. Never vmcnt(0).
// Slot s written at iter t was last read at iter t-1 before its barrier; DMA
// issued after that barrier -> no overwrite race.

#define STAGE(SLOT, TAU) do { \
  _Pragma("unroll") \
  for (int i_ = 0; i_ < 2; ++i_) { \
    const int ch_ = i_ * 1024 + tid; \
    const int row_ = ch_ >> 3; \
    const int c_ = (ch_ & 7) ^ (row_ & 7); \
    const signed char* sA_ = Aq + (size_t)(m0 + row_) * K_DIM \
                                + (size_t)(TAU) * 128 + c_ * 16; \
    __builtin_amdgcn_global_load_lds((const GAS void*)sA_, \
        (LAS void*)(lds + (SLOT) * 49152 + ch_ * 16), 16, 0, 0); \
  } \
  { \
    const int row_ = tid >> 3; \
    const int c_ = (tid & 7) ^ (row_ & 7); \
    const signed char* sB_ = Bq + (size_t)(n0 + row_) * K_DIM \
                                + (size_t)(TAU) * 128 + c_ * 16; \
    __builtin_amdgcn_global_load_lds((const GAS void*)sB_, \
        (LAS void*)(lds + (SLOT) * 49152 + 32768 + tid * 16), 16, 0, 0); \
  } \
} while (0)

#define VMW(N) asm volatile("s_waitcnt vmcnt(" #N ")" ::: "memory")
#define BAR()  do { __builtin_amdgcn_s_barrier(); asm volatile("" ::: "memory"); } while (0)

__global__ __launch_bounds__(1024, 4)
void gemm_i8(const signed char* __restrict__ Aq,
             const signed char* __restrict__ Bq,
             const float* __restrict__ scalesT,
             const float* __restrict__ sx,
             const float* __restrict__ bias,
             float* __restrict__ C) {
    __shared__ signed char lds[147456];   // 3 x 48 KB

    const int tid  = threadIdx.x;          // 0..1023
    const int l    = tid & 63;
    const int wv   = tid >> 6;             // 0..15
    const int wr   = wv >> 2;              // 0..3  (M quarter: 64 rows)
    const int wc   = wv & 3;               // 0..3  (N quarter: 32 cols)
    const int lr   = l & 15;
    const int quad = l >> 4;

    // XCD-aware swizzle: 1024 wgs = 8 XCDs x 128; per-XCD 8x16 tile rect (bijective).
    const int bid = blockIdx.x;
    const int xcd = bid & 7, kk = bid >> 3;          // kk in [0,128)
    const int by = (xcd >> 1) * 8 + (kk & 7);        // m-tile 0..31 (256-row tiles)
    const int bx = (xcd & 1) * 16 + (kk >> 3);       // n-tile 0..31 (128-col tiles)
    const int m0 = by * 256, n0 = bx * 128;

    float accf[4][2][4];
#pragma unroll
    for (int i = 0; i < 4; ++i)
#pragma unroll
        for (int j = 0; j < 2; ++j)
#pragma unroll
            for (int r = 0; r < 4; ++r) accf[i][j][r] = 0.f;

    const i32x4 izero = {0, 0, 0, 0};

    // Prologue: stage tiles 0,1 into slots 0,1. vmcnt(3) -> t0 done, t1 in flight.
    STAGE(0, 0);
    STAGE(1, 1);
    VMW(3);
    BAR();

#pragma unroll 1
    for (int t = 0; t < 32; ++t) {
        const int slot = t % 3;
        const int sl2  = (t + 2) % 3;
        const int tau2 = (t + 2) & 31;     // wrap: redundant but ledger-preserving

        // scales for this tile's group (consumed at drain; compute covers latency)
        float sj0 = scalesT[(size_t)t * N_DIM + n0 + wc * 32 + lr];
        float sj1 = scalesT[(size_t)t * N_DIM + n0 + wc * 32 + 16 + lr];

        STAGE(sl2, tau2);

        const signed char* abase = lds + slot * 49152;
        const signed char* bbase = abase + 32768;

        i32x4 ci[4][2];
#pragma unroll
        for (int ks = 0; ks < 2; ++ks) {
            i32x4 bF[2], aF[4];
#pragma unroll
            for (int nj = 0; nj < 2; ++nj) {
                const int rb = wc * 32 + nj * 16 + lr;
                bF[nj] = *(const i32x4*)(bbase + rb * 128 +
                                         ((((ks << 2) | quad) ^ (rb & 7)) << 4));
            }
#pragma unroll
            for (int mi = 0; mi < 4; ++mi) {
                const int ra = wr * 64 + mi * 16 + lr;
                aF[mi] = *(const i32x4*)(abase + ra * 128 +
                                         ((((ks << 2) | quad) ^ (ra & 7)) << 4));
            }
            __builtin_amdgcn_s_setprio(1);
#pragma unroll
            for (int mi = 0; mi < 4; ++mi)
#pragma unroll
                for (int nj = 0; nj < 2; ++nj)
                    ci[mi][nj] = __builtin_amdgcn_mfma_i32_16x16x64_i8(
                        aF[mi], bF[nj], ks ? ci[mi][nj] : izero, 0, 0, 0);
            __builtin_amdgcn_s_setprio(0);
        }

        // Drain: one pass per tile (BK=128 = one scale group, ci exact in i32).
#pragma unroll
        for (int mi = 0; mi < 4; ++mi)
#pragma unroll
            for (int r = 0; r < 4; ++r) {
                accf[mi][0][r] += sj0 * (float)ci[mi][0][r];
                accf[mi][1][r] += sj1 * (float)ci[mi][1][r];
            }

        VMW(3);   // leaves tile t+2's 3 stage loads in flight; never 0
        BAR();
    }

    // Drain wrap-staged DMA before the block exits.
    asm volatile("s_waitcnt vmcnt(0)" ::: "memory");

    // Epilogue: C/D layout col=lane&15, row=quad*4+reg (verified, dtype-independent)
    float sxr[4][4];
#pragma unroll
    for (int i = 0; i < 4; ++i)
#pragma unroll
        for (int r = 0; r < 4; ++r)
            sxr[i][r] = sx[m0 + wr * 64 + i * 16 + quad * 4 + r];
#pragma unroll
    for (int j = 0; j < 2; ++j) {
        const int gn = n0 + wc * 32 + j * 16 + lr;
        const float bv = bias[gn];
#pragma unroll
        for (int i = 0; i < 4; ++i) {
            const size_t gm = (size_t)m0 + wr * 64 + i * 16 + quad * 4;
#pragma unroll
            for (int r = 0; r < 4; ++r)
                C[(gm + r) * N_DIM + gn] = accf[i][j][r] * sxr[i][r] + bv;
        }
    }
}

extern "C" void kernel_launch(void* const* d_in, const int* in_sizes, int n_in,
                              void* d_out, int out_size, void* d_ws, size_t ws_size,
                              hipStream_t stream) {
    const float* x      = (const float*)d_in[0];   // [4,2048,4096] fp32
    const int*   wp     = (const int*)d_in[1];     // [4096,2048] int32 (uint8 semantics)
    const float* scales = (const float*)d_in[2];   // [4096,32]
    const float* bias   = (const float*)d_in[4];   // [4096]
    float* out = (float*)d_out;

    signed char* Xq = (signed char*)d_ws;                                   // 32 MB
    signed char* Wq = (signed char*)d_ws + (size_t)M_DIM * K_DIM;           // +16 MB
    float* sx  = (float*)((char*)d_ws + (size_t)M_DIM * K_DIM + (size_t)N_DIM * K_DIM);          // +32 KB
    float* scT = (float*)((char*)d_ws + (size_t)M_DIM * K_DIM + (size_t)N_DIM * K_DIM + 32768);  // +512 KB

    quant_x<<<M_DIM, 256, 0, stream>>>(x, Xq, sx);
    unpack_w<<<(N_DIM * (K_DIM / 2) / 4) / 256, 256, 0, stream>>>(wp, Wq);
    transp_scales<<<(N_DIM * 32) / 256, 256, 0, stream>>>(scales, scT);
    gemm_i8<<<dim3(1024), 1024, 0, stream>>>(Xq, Wq, scT, sx, bias, out);
}